// Round 1
// baseline (87.826 us; speedup 1.0000x reference)
//
#include <hip/hip_runtime.h>

#define KADJ 12
#define DD 128
#define BN_TOTAL 12800
#define KPAD 160      // MFMA K extent: c 0..127 = ave*adj, c=128 = wgt, 129..159 = 0
#define AROW 192      // LDS A row stride in bf16 elems (24 x 16B units, room for XOR swizzle)

typedef float f32x4 __attribute__((ext_vector_type(4)));
typedef __bf16 bf16x8 __attribute__((ext_vector_type(8)));

__device__ __forceinline__ unsigned short f2bf(float x) {
    unsigned u = __builtin_bit_cast(unsigned, x);
    u += 0x7FFFu + ((u >> 16) & 1u);   // round-to-nearest-even
    return (unsigned short)(u >> 16);
}

// ---------------- K0: w1[129][128] -> w1t[d][k] bf16, K padded to 160 ----------------
__global__ void k_w1t(const float* __restrict__ w1, unsigned short* __restrict__ w1t) {
    int k = blockIdx.x;       // 0..159
    int d = threadIdx.x;      // 0..127
    float v = (k < 129) ? w1[k * DD + d] : 0.f;
    w1t[d * KPAD + k] = f2bf(v);
}

// ---------------- K1: per (b,n): h = A@w1 (MFMA bf16), leaky, @w2, softmax, att ------
__launch_bounds__(256)
__global__ void k_att(const float* __restrict__ ave, const float* __restrict__ adj,
                      const float* __restrict__ wgt, const float* __restrict__ w2,
                      const unsigned short* __restrict__ w1t, float* __restrict__ att_out) {
    __shared__ unsigned short abuf[4][16 * AROW];   // per-wave A tile, swizzled
    __shared__ float w2s[DD];
    __shared__ float sbuf[4][16];

    const int t = threadIdx.x;
    const int w = t >> 6;          // wave 0..3
    const int lane = t & 63;
    const int bn = blockIdx.x * 4 + w;

    // zero all A tiles (covers pad rows 12..15 and k 129..191)
    {
        f32x4* z = reinterpret_cast<f32x4*>(&abuf[0][0]);
        #pragma unroll
        for (int i = 0; i < 6; ++i) z[i * 256 + t] = f32x4{0.f, 0.f, 0.f, 0.f};
        if (t < DD) w2s[t] = w2[t];
    }
    __syncthreads();

    // fill A: a[r][c] = ave[c]*adj[r][c] (c<128), a[r][128] = wgt[r]; XOR-swizzled 16B units
    {
        const float* avep = ave + (size_t)bn * DD;
        const float* adjp = adj + (size_t)bn * KADJ * DD;
        float av0 = avep[lane];
        float av1 = avep[lane + 64];
        unsigned short* ab = abuf[w];
        #pragma unroll
        for (int r = 0; r < KADJ; ++r) {
            float x0 = av0 * adjp[r * DD + lane];
            float x1 = av1 * adjp[r * DD + lane + 64];
            int c0 = lane, c1 = lane + 64;
            ab[r * AROW + (((c0 >> 3) ^ (r & 7)) << 3) + (c0 & 7)] = f2bf(x0);
            ab[r * AROW + (((c1 >> 3) ^ (r & 7)) << 3) + (c1 & 7)] = f2bf(x1);
        }
        if (lane < KADJ)
            ab[lane * AROW + ((16 ^ (lane & 7)) << 3)] = f2bf(wgt[(size_t)bn * KADJ + lane]);
    }
    __syncthreads();

    // MFMA: C[16x128] = A[16x160] @ w1t^T ; A-frags from LDS, B-frags from global (L2)
    const int l = lane & 15, g = lane >> 4;
    bf16x8 af[5];
    {
        const unsigned short* ab = abuf[w] + l * AROW;
        #pragma unroll
        for (int s = 0; s < 5; ++s)
            af[s] = *reinterpret_cast<const bf16x8*>(ab + ((((s * 4 + g) ^ (l & 7))) << 3));
    }
    f32x4 acc[8];
    #pragma unroll
    for (int n = 0; n < 8; ++n) acc[n] = f32x4{0.f, 0.f, 0.f, 0.f};

    #pragma unroll
    for (int n = 0; n < 8; ++n) {
        const unsigned short* bp = w1t + (size_t)(n * 16 + l) * KPAD + g * 8;
        #pragma unroll
        for (int s = 0; s < 5; ++s) {
            bf16x8 bfr = *reinterpret_cast<const bf16x8*>(bp + s * 32);
            acc[n] = __builtin_amdgcn_mfma_f32_16x16x32_bf16(af[s], bfr, acc[n], 0, 0, 0);
        }
    }

    // epilogue: leaky-relu, dot with w2 (partial over this lane's 8 cols)
    float p[4] = {0.f, 0.f, 0.f, 0.f};
    #pragma unroll
    for (int n = 0; n < 8; ++n) {
        float w2c = w2s[n * 16 + l];
        #pragma unroll
        for (int j = 0; j < 4; ++j) {
            float h = acc[n][j];
            h = h > 0.f ? h : 0.2f * h;
            p[j] = fmaf(h, w2c, p[j]);
        }
    }
    // reduce over the 16 lanes sharing the same row-group
    #pragma unroll
    for (int j = 0; j < 4; ++j) {
        #pragma unroll
        for (int m = 1; m < 16; m <<= 1) p[j] += __shfl_xor(p[j], m, 64);
    }
    if (l == 0 && g < 3) {
        #pragma unroll
        for (int j = 0; j < 4; ++j) sbuf[w][g * 4 + j] = p[j];
    }
    // (same-wave LDS write->read: ordered; compiler inserts lgkmcnt wait via may-alias dep)

    // softmax over K=12 (all lanes, redundant)
    float al[KADJ];
    {
        float mx = -1e30f;
        #pragma unroll
        for (int k = 0; k < KADJ; ++k) { al[k] = sbuf[w][k]; mx = fmaxf(mx, al[k]); }
        float sum = 0.f;
        #pragma unroll
        for (int k = 0; k < KADJ; ++k) { al[k] = __expf(al[k] - mx); sum += al[k]; }
        float inv = 1.f / sum;
        #pragma unroll
        for (int k = 0; k < KADJ; ++k) al[k] *= inv;
    }

    // att[c] = sum_k alpha_k * adj[k][c]; k split across g-groups, then shfl-reduce
    float attv[8] = {0.f, 0.f, 0.f, 0.f, 0.f, 0.f, 0.f, 0.f};
    const float* adjp = adj + (size_t)bn * KADJ * DD;
    #pragma unroll
    for (int kk = 0; kk < 3; ++kk) {
        int k = g * 3 + kk;
        float a_ = al[k];
        #pragma unroll
        for (int n = 0; n < 8; ++n)
            attv[n] = fmaf(a_, adjp[k * DD + n * 16 + l], attv[n]);
    }
    #pragma unroll
    for (int n = 0; n < 8; ++n) {
        attv[n] += __shfl_xor(attv[n], 16, 64);
        attv[n] += __shfl_xor(attv[n], 32, 64);
    }
    if (g == 0) {
        #pragma unroll
        for (int n = 0; n < 8; ++n)
            att_out[(size_t)bn * DD + n * 16 + l] = attv[n];
    }
}

// ---------------- K2: out = relu([itm | att] @ w3), att read from d_out, overwritten --
__launch_bounds__(256)
__global__ void k_out(const float* __restrict__ itm, const float* __restrict__ attb,
                      const float* __restrict__ w3, float* __restrict__ outp) {
    __shared__ float in_lds[32 * 264];
    const int t = threadIdx.x;
    const int R0 = blockIdx.x * 32;

    #pragma unroll
    for (int i = 0; i < 32; ++i) {
        int idx = i * 256 + t;
        int r = idx >> 8, c = idx & 255;
        float v = (c < DD) ? itm[(size_t)(R0 + r) * DD + c]
                           : attb[(size_t)(R0 + r) * DD + (c - DD)];
        in_lds[r * 264 + c] = v;
    }
    __syncthreads();   // all att values are in LDS before we overwrite d_out rows

    const int dg = t & 15, rg = t >> 4;
    const int d0 = dg * 8;
    const int r0 = rg * 2;

    f32x4 acc0a{0.f,0.f,0.f,0.f}, acc0b{0.f,0.f,0.f,0.f};
    f32x4 acc1a{0.f,0.f,0.f,0.f}, acc1b{0.f,0.f,0.f,0.f};

    #pragma unroll 2
    for (int c = 0; c < 256; c += 4) {
        f32x4 a0 = *reinterpret_cast<const f32x4*>(&in_lds[r0 * 264 + c]);
        f32x4 a1 = *reinterpret_cast<const f32x4*>(&in_lds[(r0 + 1) * 264 + c]);
        #pragma unroll
        for (int i = 0; i < 4; ++i) {
            f32x4 b0 = *reinterpret_cast<const f32x4*>(&w3[(size_t)(c + i) * DD + d0]);
            f32x4 b1 = *reinterpret_cast<const f32x4*>(&w3[(size_t)(c + i) * DD + d0 + 4]);
            acc0a += a0[i] * b0;  acc0b += a0[i] * b1;
            acc1a += a1[i] * b0;  acc1b += a1[i] * b1;
        }
    }

    #pragma unroll
    for (int i = 0; i < 4; ++i) {
        acc0a[i] = fmaxf(acc0a[i], 0.f); acc0b[i] = fmaxf(acc0b[i], 0.f);
        acc1a[i] = fmaxf(acc1a[i], 0.f); acc1b[i] = fmaxf(acc1b[i], 0.f);
    }
    *reinterpret_cast<f32x4*>(&outp[(size_t)(R0 + r0) * DD + d0])         = acc0a;
    *reinterpret_cast<f32x4*>(&outp[(size_t)(R0 + r0) * DD + d0 + 4])     = acc0b;
    *reinterpret_cast<f32x4*>(&outp[(size_t)(R0 + r0 + 1) * DD + d0])     = acc1a;
    *reinterpret_cast<f32x4*>(&outp[(size_t)(R0 + r0 + 1) * DD + d0 + 4]) = acc1b;
}

extern "C" void kernel_launch(void* const* d_in, const int* in_sizes, int n_in,
                              void* d_out, int out_size, void* d_ws, size_t ws_size,
                              hipStream_t stream) {
    const float* itm = (const float*)d_in[1];
    const float* ave = (const float*)d_in[2];
    const float* adj = (const float*)d_in[3];
    const float* wgt = (const float*)d_in[4];
    const float* w1  = (const float*)d_in[5];
    const float* w2  = (const float*)d_in[6];
    const float* w3  = (const float*)d_in[7];
    float* outp = (float*)d_out;
    unsigned short* w1t = (unsigned short*)d_ws;   // 128*160*2 = 40 KB

    k_w1t<<<dim3(KPAD), dim3(DD), 0, stream>>>(w1, w1t);
    k_att<<<dim3(BN_TOTAL / 4), dim3(256), 0, stream>>>(ave, adj, wgt, w2, w1t, outp);
    k_out<<<dim3(BN_TOTAL / 32), dim3(256), 0, stream>>>(itm, outp, w3, outp);
}